// Round 10
// baseline (159.549 us; speedup 1.0000x reference)
//
#include <hip/hip_runtime.h>
#include <math.h>

#define NN 1024     // entities
#define HD 128      // hidden dim
#define NH 8        // heads
#define CH 16       // dim per head
#define NLAYERS 3

#define TT 8        // targets per attention block
#define ALP 130     // k_edge_w al row stride
#define PBM 4       // k_proj rows per block
#define ABM 2       // k_edge_ab rows per block
#define QSC 0.36067376022224085f   // 0.25 * log2(e)

__device__ __forceinline__ float bf16_to_f32(unsigned short u) {
    union { unsigned int i; float f; } x; x.i = ((unsigned int)u) << 16; return x.f;
}
__device__ __forceinline__ unsigned short f32_to_bf16(float f) {
    union { float f; unsigned int i; } x; x.f = f;
    const unsigned int r = x.i + 0x7FFFu + ((x.i >> 16) & 1u);   // RNE
    return (unsigned short)(r >> 16);
}

// ---------------- K1: a = x@W1[:128], b = x@W1[128:] + b1; by==0 also copies x -> xout ----------------
__global__ __launch_bounds__(256) void k_edge_ab(
        const float* __restrict__ x, const float* __restrict__ W1,
        const float* __restrict__ b1, float* __restrict__ a, float* __restrict__ b,
        float* __restrict__ xout) {
    __shared__ float xt[HD][ABM];        // x transposed: xt[kk][r]
    __shared__ float red[2][ABM][HD];    // kk-group partials
    const int r0 = blockIdx.x * ABM;
    const int cb = blockIdx.y;           // 0 -> a, 1 -> b
    const int t  = threadIdx.x;
    {
        const float xv = x[(r0 + (t >> 7)) * HD + (t & 127)];
        xt[t & 127][t >> 7] = xv;
        if (cb == 0) xout[(r0 + (t >> 7)) * HD + (t & 127)] = xv;   // fused x init
    }
    __syncthreads();
    const int c = t & 127, g = t >> 7;   // col, kk-group
    const float* wp = W1 + cb * HD * HD + g * 64 * HD + c;
    const float* xp = &xt[g * 64][0];
    float a0 = 0.f, a1 = 0.f;
    #pragma unroll 8
    for (int kk = 0; kk < 64; ++kk) {
        const float wv = wp[kk * HD];                         // coalesced 256B/wave
        const float2 xv = *(const float2*)&xp[kk * ABM];      // uniform ds_read_b64 (broadcast)
        a0 = fmaf(xv.x, wv, a0);
        a1 = fmaf(xv.y, wv, a1);
    }
    red[g][0][c] = a0; red[g][1][c] = a1;
    __syncthreads();
    if (t < HD) {
        float* dst = cb ? b : a;
        const float bias = cb ? b1[t] : 0.f;                  // fold b1 into b
        #pragma unroll
        for (int r = 0; r < ABM; ++r)
            dst[(r0 + r) * HD + t] = red[0][r][t] + red[1][r][t] + bias;
    }
}

// ---------------- K2: wm[t][s] = bf16( sign(mask) * sigmoid(logit[s][t]) ) ----------------
__global__ __launch_bounds__(256) void k_edge_w(
        const float* __restrict__ a, const float* __restrict__ bb,
        const float* __restrict__ W2, const float* __restrict__ b2,
        unsigned short* __restrict__ wm) {
    __shared__ float al[32][ALP];
    __shared__ float bl[16][HD];
    const int t = threadIdx.x;
    const int s0 = blockIdx.x * 32, t0 = blockIdx.y * 16;
    for (int ii = t; ii < 2048; ii += 256) {
        const int row = ii >> 6, col = (ii & 63) * 2;
        *(float2*)&al[row][col] = *(const float2*)&a[(s0 + row) * HD + col];
    }
    for (int ii = t; ii < 512; ii += 256) {
        const int row = ii >> 5, col = (ii & 31) * 4;
        *(float4*)&bl[row][col] = *(const float4*)&bb[(t0 + row) * HD + col];
    }
    __syncthreads();
    const int s = t & 31, tt = t >> 5;
    float acc0 = 0.f, acc1 = 0.f;
    #pragma unroll 2
    for (int h4 = 0; h4 < HD; h4 += 4) {
        const float4 w2 = *(const float4*)&W2[h4];          // uniform -> s_load_dwordx4
        const float2 avA = *(const float2*)&al[s][h4];
        const float2 avB = *(const float2*)&al[s][h4 + 2];
        const float4 b0v = *(const float4*)&bl[tt][h4];
        const float4 b1v = *(const float4*)&bl[tt + 8][h4];
        acc0 = fmaf(fmaxf(avA.x + b0v.x, 0.f), w2.x, acc0);
        acc0 = fmaf(fmaxf(avA.y + b0v.y, 0.f), w2.y, acc0);
        acc0 = fmaf(fmaxf(avB.x + b0v.z, 0.f), w2.z, acc0);
        acc0 = fmaf(fmaxf(avB.y + b0v.w, 0.f), w2.w, acc0);
        acc1 = fmaf(fmaxf(avA.x + b1v.x, 0.f), w2.x, acc1);
        acc1 = fmaf(fmaxf(avA.y + b1v.y, 0.f), w2.y, acc1);
        acc1 = fmaf(fmaxf(avB.x + b1v.z, 0.f), w2.z, acc1);
        acc1 = fmaf(fmaxf(avB.y + b1v.w, 0.f), w2.w, acc1);
    }
    const float bias = b2[0];
    const float l0 = acc0 + bias, l1 = acc1 + bias;
    const float w0 = 1.f / (1.f + __expf(-l0));
    const float w1 = 1.f / (1.f + __expf(-l1));
    wm[(t0 + tt    ) * NN + s0 + s] = f32_to_bf16((l0 > 0.f) ? w0 : -w0);   // sign encodes mask
    wm[(t0 + tt + 8) * NN + s0 + s] = f32_to_bf16((l1 > 0.f) ? w1 : -w1);
}

// ---------------- K3: projections q,k,v ([h][n][c]) + skip ----------------
// grid (NN/PBM, 4): by selects matrix {Wq,Wk,Wv,Ws}. 1024 blocks, kk-split x2.
__global__ __launch_bounds__(256) void k_proj(
        const float* __restrict__ x,
        const float* __restrict__ Wq, const float* __restrict__ bq,
        const float* __restrict__ Wk, const float* __restrict__ bk,
        const float* __restrict__ Wv, const float* __restrict__ bv,
        const float* __restrict__ Wsk, const float* __restrict__ bsk,
        float* __restrict__ q, float* __restrict__ k,
        float* __restrict__ v, float* __restrict__ skip) {
    __shared__ float xt[HD][PBM];        // x transposed: xt[kk][r]
    __shared__ float red[2][PBM][HD];    // kk-group partials
    const int r0 = blockIdx.x * PBM;
    const int cb = blockIdx.y;           // 0..3 -> q,k,v,skip
    const int t  = threadIdx.x;
    {   // stage 4x128 transposed (one-time; write conflicts negligible)
        const int r = t >> 6, c2 = (t & 63) * 2;
        const float2 xv = *(const float2*)&x[(r0 + r) * HD + c2];
        xt[c2][r] = xv.x; xt[c2 + 1][r] = xv.y;
    }
    __syncthreads();
    const int c = t & 127, g = t >> 7;   // col within matrix, kk-group
    const float* W = (cb == 0) ? Wq : (cb == 1) ? Wk : (cb == 2) ? Wv : Wsk;
    const float* wp = W + g * 64 * HD + c;
    const float* xp = &xt[g * 64][0];
    float a0 = 0.f, a1 = 0.f, a2 = 0.f, a3 = 0.f;
    #pragma unroll 8
    for (int kk = 0; kk < 64; ++kk) {
        const float wv = wp[kk * HD];                         // coalesced 256B/wave
        const float4 xv = *(const float4*)&xp[kk * PBM];      // uniform ds_read_b128 (broadcast)
        a0 = fmaf(xv.x, wv, a0);
        a1 = fmaf(xv.y, wv, a1);
        a2 = fmaf(xv.z, wv, a2);
        a3 = fmaf(xv.w, wv, a3);
    }
    red[g][0][c] = a0; red[g][1][c] = a1; red[g][2][c] = a2; red[g][3][c] = a3;
    __syncthreads();
    if (t < HD) {
        const float* bptr = (cb == 0) ? bq : (cb == 1) ? bk : (cb == 2) ? bv : bsk;
        const float bias = bptr[t];
        #pragma unroll
        for (int r = 0; r < PBM; ++r) {
            const float val = red[0][r][t] + red[1][r][t] + bias;
            const int row = r0 + r;
            if (cb == 3) {
                skip[row * HD + t] = val;
            } else {
                const int hnc = (t >> 4) * (NN * CH) + row * CH + (t & 15);
                ((cb == 0) ? q : (cb == 1) ? k : v)[hnc] = val;
            }
        }
    }
}

// ---------------- K4: fused attention, one (head, 8-target tile); wave owns 2 rows ----------------
__global__ __launch_bounds__(256) void k_attn(
        const float* __restrict__ q, const float* __restrict__ k,
        const float* __restrict__ v, const float* __restrict__ skip,
        const unsigned short* __restrict__ wm, const float* __restrict__ We,
        float* __restrict__ x) {
    __shared__ float s_tile[TT][NN];   // 32 KB; rows accessed j-consecutive only
    __shared__ float q_l[TT][CH];      // q * 0.25*log2e (exp2-domain scale folded)
    __shared__ float mpart[TT];        // row maxima (single-owner waves)
    const int h  = blockIdx.x;
    const int i0 = blockIdx.y * TT;
    const int t  = threadIdx.x;

    if (t < TT * CH) q_l[t >> 4][t & 15] = q[h * (NN * CH) + (i0 + (t >> 4)) * CH + (t & 15)] * QSC;
    __syncthreads();

    const int g = t >> 6;              // wave id: owns rows 2g, 2g+1
    const int l = t & 63;

    // ---- phase 1: logits (exp2 domain) + online row max ----
    float qr0[CH], qr1[CH];
    float qe0 = 0.f, qe1 = 0.f;
    #pragma unroll
    for (int c = 0; c < CH; ++c) {
        qr0[c] = q_l[2 * g][c];
        qr1[c] = q_l[2 * g + 1][c];
        const float we = We[h * CH + c];           // uniform -> scalar loads
        qe0 = fmaf(qr0[c], we, qe0);
        qe1 = fmaf(qr1[c], we, qe1);
    }
    const float* kh = k + h * (NN * CH);
    const unsigned short* wr0 = wm + (i0 + 2 * g) * NN;
    const unsigned short* wr1 = wr0 + NN;
    float ml0 = -1e30f, ml1 = -1e30f;
    #pragma unroll 1
    for (int p = 0; p < 16; ++p) {
        const int j = l + 64 * p;
        const float4* kp = (const float4*)(kh + j * CH);
        const float4 r0 = kp[0], r1 = kp[1], r2 = kp[2], r3 = kp[3];
        const float kr[CH] = {r0.x, r0.y, r0.z, r0.w, r1.x, r1.y, r1.z, r1.w,
                              r2.x, r2.y, r2.z, r2.w, r3.x, r3.y, r3.z, r3.w};
        float d0 = 0.f, d1 = 0.f;
        #pragma unroll
        for (int c = 0; c < CH; ++c) {
            d0 = fmaf(qr0[c], kr[c], d0);
            d1 = fmaf(qr1[c], kr[c], d1);
        }
        const float w0 = bf16_to_f32(wr0[j]);
        const float w1 = bf16_to_f32(wr1[j]);
        float s0 = d0 + qe0 * fabsf(w0);
        float s1 = d1 + qe1 * fabsf(w1);
        s0 = (w0 > 0.f) ? s0 : -1e30f;             // sign = mask
        s1 = (w1 > 0.f) ? s1 : -1e30f;
        s_tile[2 * g][j] = s0;
        s_tile[2 * g + 1][j] = s1;
        ml0 = fmaxf(ml0, s0);
        ml1 = fmaxf(ml1, s1);
    }
    #pragma unroll
    for (int off = 1; off < 64; off <<= 1) {
        ml0 = fmaxf(ml0, __shfl_xor(ml0, off));
        ml1 = fmaxf(ml1, __shfl_xor(ml1, off));
    }
    if (l == 0) { mpart[2 * g] = ml0; mpart[2 * g + 1] = ml1; }
    __syncthreads();

    // ---- phase 2: p = exp2(s - m) (masked underflows to 0), accumulate o/sum/aw ----
    const float m0 = mpart[2 * g], m1 = mpart[2 * g + 1];
    const float* vh = v + h * (NN * CH);
    float o0[CH], o1[CH];
    #pragma unroll
    for (int c = 0; c < CH; ++c) { o0[c] = 0.f; o1[c] = 0.f; }
    float sum0 = 0.f, sum1 = 0.f, aw0 = 0.f, aw1 = 0.f;
    #pragma unroll 1
    for (int it = 0; it < 16; ++it) {
        const int j = l + 64 * it;
        const float4* vp = (const float4*)(vh + j * CH);
        const float4 v0 = vp[0], v1 = vp[1], v2 = vp[2], v3 = vp[3];
        const float vv[CH] = {v0.x, v0.y, v0.z, v0.w, v1.x, v1.y, v1.z, v1.w,
                              v2.x, v2.y, v2.z, v2.w, v3.x, v3.y, v3.z, v3.w};
        const float p0 = __builtin_amdgcn_exp2f(s_tile[2 * g][j] - m0);
        const float p1 = __builtin_amdgcn_exp2f(s_tile[2 * g + 1][j] - m1);
        const float w0 = fabsf(bf16_to_f32(wr0[j]));
        const float w1 = fabsf(bf16_to_f32(wr1[j]));
        sum0 += p0; sum1 += p1;
        aw0 = fmaf(p0, w0, aw0);
        aw1 = fmaf(p1, w1, aw1);
        #pragma unroll
        for (int c = 0; c < CH; ++c) {
            o0[c] = fmaf(p0, vv[c], o0[c]);
            o1[c] = fmaf(p1, vv[c], o1[c]);
        }
    }
    #pragma unroll
    for (int off = 1; off < 64; off <<= 1) {
        #pragma unroll
        for (int c = 0; c < CH; ++c) {
            o0[c] += __shfl_xor(o0[c], off);
            o1[c] += __shfl_xor(o1[c], off);
        }
        sum0 += __shfl_xor(sum0, off);
        sum1 += __shfl_xor(sum1, off);
        aw0 += __shfl_xor(aw0, off);
        aw1 += __shfl_xor(aw1, off);
    }
    // lane 0 -> row 2g, lane 32 -> row 2g+1 (all lanes hold totals after full butterfly)
    if ((l & 31) == 0) {
        const int hi = l >> 5;
        const float m   = hi ? m1 : m0;
        const float sum = hi ? sum1 : sum0;
        const float aw  = hi ? aw1 : aw0;
        const float inv = (m > -1e29f) ? 1.f / sum : 0.f;   // all-masked row -> 0
        const float awv = aw * inv;
        float oc[CH];
        #pragma unroll
        for (int c = 0; c < CH; ++c) oc[c] = hi ? o1[c] : o0[c];
        const int base = (i0 + 2 * g + hi) * HD + h * CH;
        #pragma unroll
        for (int cc = 0; cc < 4; ++cc) {
            const float4 we4 = *(const float4*)&We[h * CH + cc * 4];
            const float4 xo  = *(const float4*)&x[base + cc * 4];
            const float4 so  = *(const float4*)&skip[base + cc * 4];
            float4 o;
            o.x = xo.x + so.x + oc[cc * 4 + 0] * inv + awv * we4.x;
            o.y = xo.y + so.y + oc[cc * 4 + 1] * inv + awv * we4.y;
            o.z = xo.z + so.z + oc[cc * 4 + 2] * inv + awv * we4.z;
            o.w = xo.w + so.w + oc[cc * 4 + 3] * inv + awv * we4.w;
            *(float4*)&x[base + cc * 4] = o;       // slice owned exclusively by this wave
        }
    }
}

// ---------------- launch ----------------
extern "C" void kernel_launch(void* const* d_in, const int* in_sizes, int n_in,
                              void* d_out, int out_size, void* d_ws, size_t ws_size,
                              hipStream_t stream) {
    const float* ent = (const float*)d_in[2];
    const float* W1  = (const float*)d_in[3];
    const float* b1  = (const float*)d_in[4];
    const float* W2  = (const float*)d_in[5];
    const float* b2  = (const float*)d_in[6];
    const float* Wq  = (const float*)d_in[7];
    const float* bq  = (const float*)d_in[8];
    const float* Wk  = (const float*)d_in[9];
    const float* bk  = (const float*)d_in[10];
    const float* Wv  = (const float*)d_in[11];
    const float* bv  = (const float*)d_in[12];
    const float* We  = (const float*)d_in[13];
    const float* Ws  = (const float*)d_in[14];
    const float* bs  = (const float*)d_in[15];

    unsigned short* wm = (unsigned short*)d_ws;   // [1024][1024] bf16, sign = mask (2 MB)
    float* fb = (float*)d_ws + (NN * NN / 2);     // float area after wm
    float* q  = fb;                               // [8][1024][16]  (reused as 'a' before layers)
    float* k  = q + NN * HD;                      //                (reused as 'b')
    float* v  = k + NN * HD;                      // [8][1024][16]
    float* sk = v + NN * HD;
    float* x  = (float*)d_out;                    // running entity state

    k_edge_ab<<<dim3(NN / ABM, 2), 256, 0, stream>>>(ent, W1, b1, q /*a*/, k /*b*/, x);
    k_edge_w<<<dim3(32, 64), 256, 0, stream>>>(q, k, W2, b2, wm);

    for (int l = 0; l < NLAYERS; ++l) {
        k_proj<<<dim3(NN / PBM, 4), 256, 0, stream>>>(x,
            Wq + l * HD * HD, bq + l * HD, Wk + l * HD * HD, bk + l * HD,
            Wv + l * HD * HD, bv + l * HD, Ws + l * HD * HD, bs + l * HD,
            q, k, v, sk);
        k_attn<<<dim3(NH, NN / TT), 256, 0, stream>>>(q, k, v, sk, wm, We + l * HD, x);
    }
}

// Round 11
// 112.273 us; speedup vs baseline: 1.4211x; 1.4211x over previous
//
#include <hip/hip_runtime.h>
#include <math.h>

#define NN 1024     // entities
#define HD 128      // hidden dim
#define NH 8        // heads
#define CH 16       // dim per head
#define NLAYERS 3

#define TT 8        // target rows per attention block
#define CHK 128     // j-chunk size staged in LDS
#define KSP 20      // kS/vS row stride (floats): 80B -> b128 reads conflict-free across js, 16B aligned
#define ALP 130     // k_edge_w al row stride
#define PBM 4       // k_proj rows per block
#define ABM 2       // k_edge_ab rows per block
#define QSC 0.36067376022224085f   // 0.25 * log2(e)

__device__ __forceinline__ float bf16_to_f32(unsigned short u) {
    union { unsigned int i; float f; } x; x.i = ((unsigned int)u) << 16; return x.f;
}
__device__ __forceinline__ unsigned short f32_to_bf16(float f) {
    union { float f; unsigned int i; } x; x.f = f;
    const unsigned int r = x.i + 0x7FFFu + ((x.i >> 16) & 1u);   // RNE
    return (unsigned short)(r >> 16);
}

// ---------------- K1: a = x@W1[:128], b = x@W1[128:] + b1; by==0 also copies x -> xout ----------------
__global__ __launch_bounds__(256) void k_edge_ab(
        const float* __restrict__ x, const float* __restrict__ W1,
        const float* __restrict__ b1, float* __restrict__ a, float* __restrict__ b,
        float* __restrict__ xout) {
    __shared__ float xt[HD][ABM];
    __shared__ float red[2][ABM][HD];
    const int r0 = blockIdx.x * ABM;
    const int cb = blockIdx.y;           // 0 -> a, 1 -> b
    const int t  = threadIdx.x;
    {
        const float xv = x[(r0 + (t >> 7)) * HD + (t & 127)];
        xt[t & 127][t >> 7] = xv;
        if (cb == 0) xout[(r0 + (t >> 7)) * HD + (t & 127)] = xv;   // fused x init
    }
    __syncthreads();
    const int c = t & 127, g = t >> 7;
    const float* wp = W1 + cb * HD * HD + g * 64 * HD + c;
    const float* xp = &xt[g * 64][0];
    float a0 = 0.f, a1 = 0.f;
    #pragma unroll 8
    for (int kk = 0; kk < 64; ++kk) {
        const float wv = wp[kk * HD];
        const float2 xv = *(const float2*)&xp[kk * ABM];
        a0 = fmaf(xv.x, wv, a0);
        a1 = fmaf(xv.y, wv, a1);
    }
    red[g][0][c] = a0; red[g][1][c] = a1;
    __syncthreads();
    if (t < HD) {
        float* dst = cb ? b : a;
        const float bias = cb ? b1[t] : 0.f;
        #pragma unroll
        for (int r = 0; r < ABM; ++r)
            dst[(r0 + r) * HD + t] = red[0][r][t] + red[1][r][t] + bias;
    }
}

// ---------------- K2: wm[t][s] = bf16( sign(mask) * sigmoid(logit[s][t]) ) ----------------
__global__ __launch_bounds__(256) void k_edge_w(
        const float* __restrict__ a, const float* __restrict__ bb,
        const float* __restrict__ W2, const float* __restrict__ b2,
        unsigned short* __restrict__ wm) {
    __shared__ float al[32][ALP];
    __shared__ float bl[16][HD];
    const int t = threadIdx.x;
    const int s0 = blockIdx.x * 32, t0 = blockIdx.y * 16;
    for (int ii = t; ii < 2048; ii += 256) {
        const int row = ii >> 6, col = (ii & 63) * 2;
        *(float2*)&al[row][col] = *(const float2*)&a[(s0 + row) * HD + col];
    }
    for (int ii = t; ii < 512; ii += 256) {
        const int row = ii >> 5, col = (ii & 31) * 4;
        *(float4*)&bl[row][col] = *(const float4*)&bb[(t0 + row) * HD + col];
    }
    __syncthreads();
    const int s = t & 31, tt = t >> 5;
    float acc0 = 0.f, acc1 = 0.f;
    #pragma unroll 2
    for (int h4 = 0; h4 < HD; h4 += 4) {
        const float4 w2 = *(const float4*)&W2[h4];
        const float2 avA = *(const float2*)&al[s][h4];
        const float2 avB = *(const float2*)&al[s][h4 + 2];
        const float4 b0v = *(const float4*)&bl[tt][h4];
        const float4 b1v = *(const float4*)&bl[tt + 8][h4];
        acc0 = fmaf(fmaxf(avA.x + b0v.x, 0.f), w2.x, acc0);
        acc0 = fmaf(fmaxf(avA.y + b0v.y, 0.f), w2.y, acc0);
        acc0 = fmaf(fmaxf(avB.x + b0v.z, 0.f), w2.z, acc0);
        acc0 = fmaf(fmaxf(avB.y + b0v.w, 0.f), w2.w, acc0);
        acc1 = fmaf(fmaxf(avA.x + b1v.x, 0.f), w2.x, acc1);
        acc1 = fmaf(fmaxf(avA.y + b1v.y, 0.f), w2.y, acc1);
        acc1 = fmaf(fmaxf(avB.x + b1v.z, 0.f), w2.z, acc1);
        acc1 = fmaf(fmaxf(avB.y + b1v.w, 0.f), w2.w, acc1);
    }
    const float bias = b2[0];
    const float l0 = acc0 + bias, l1 = acc1 + bias;
    const float w0 = 1.f / (1.f + __expf(-l0));
    const float w1 = 1.f / (1.f + __expf(-l1));
    wm[(t0 + tt    ) * NN + s0 + s] = f32_to_bf16((l0 > 0.f) ? w0 : -w0);   // sign encodes mask
    wm[(t0 + tt + 8) * NN + s0 + s] = f32_to_bf16((l1 > 0.f) ? w1 : -w1);
}

// ---------------- K3: projections q,k,v ([h][n][c]) + skip ----------------
__global__ __launch_bounds__(256) void k_proj(
        const float* __restrict__ x,
        const float* __restrict__ Wq, const float* __restrict__ bq,
        const float* __restrict__ Wk, const float* __restrict__ bk,
        const float* __restrict__ Wv, const float* __restrict__ bv,
        const float* __restrict__ Wsk, const float* __restrict__ bsk,
        float* __restrict__ q, float* __restrict__ k,
        float* __restrict__ v, float* __restrict__ skip) {
    __shared__ float xt[HD][PBM];
    __shared__ float red[2][PBM][HD];
    const int r0 = blockIdx.x * PBM;
    const int cb = blockIdx.y;           // 0..3 -> q,k,v,skip
    const int t  = threadIdx.x;
    {
        const int r = t >> 6, c2 = (t & 63) * 2;
        const float2 xv = *(const float2*)&x[(r0 + r) * HD + c2];
        xt[c2][r] = xv.x; xt[c2 + 1][r] = xv.y;
    }
    __syncthreads();
    const int c = t & 127, g = t >> 7;
    const float* W = (cb == 0) ? Wq : (cb == 1) ? Wk : (cb == 2) ? Wv : Wsk;
    const float* wp = W + g * 64 * HD + c;
    const float* xp = &xt[g * 64][0];
    float a0 = 0.f, a1 = 0.f, a2 = 0.f, a3 = 0.f;
    #pragma unroll 8
    for (int kk = 0; kk < 64; ++kk) {
        const float wv = wp[kk * HD];
        const float4 xv = *(const float4*)&xp[kk * PBM];
        a0 = fmaf(xv.x, wv, a0);
        a1 = fmaf(xv.y, wv, a1);
        a2 = fmaf(xv.z, wv, a2);
        a3 = fmaf(xv.w, wv, a3);
    }
    red[g][0][c] = a0; red[g][1][c] = a1; red[g][2][c] = a2; red[g][3][c] = a3;
    __syncthreads();
    if (t < HD) {
        const float* bptr = (cb == 0) ? bq : (cb == 1) ? bk : (cb == 2) ? bv : bsk;
        const float bias = bptr[t];
        #pragma unroll
        for (int r = 0; r < PBM; ++r) {
            const float val = red[0][r][t] + red[1][r][t] + bias;
            const int row = r0 + r;
            if (cb == 3) {
                skip[row * HD + t] = val;
            } else {
                const int hnc = (t >> 4) * (NN * CH) + row * CH + (t & 15);
                ((cb == 0) ? q : (cb == 1) ? k : v)[hnc] = val;
            }
        }
    }
}

// ---------------- K4: flash-style fused attention; LDS-staged k/v chunks ----------------
// grid (NN/TT, NH) tile-major. Block: 4 waves; lane = (row r, j-slot js);
// wave w covers j-quarter of each 128-chunk for ALL 8 rows; online softmax per lane.
__global__ __launch_bounds__(256) void k_attn(
        const float* __restrict__ q, const float* __restrict__ k,
        const float* __restrict__ v, const float* __restrict__ skip,
        const unsigned short* __restrict__ wm, const float* __restrict__ We,
        float* __restrict__ x) {
    __shared__ float kS[CHK][KSP];       // 10 KB
    __shared__ float vS[CHK][KSP];       // 10 KB
    __shared__ float mrg[4][TT][20];     // 2.5 KB: per-wave partials {m,sum,aw,o[16]}
    const int i0 = blockIdx.x * TT;
    const int h  = blockIdx.y;
    const int t  = threadIdx.x;
    const int w  = t >> 6, l = t & 63;
    const int r  = l >> 3, js = l & 7;

    // q row (broadcast within 8-lane group), scaled into exp2 domain
    float qr[CH];
    {
        const float* qp = q + h * (NN * CH) + (i0 + r) * CH;
        const float4 q0 = *(const float4*)(qp + 0);
        const float4 q1 = *(const float4*)(qp + 4);
        const float4 q2 = *(const float4*)(qp + 8);
        const float4 q3 = *(const float4*)(qp + 12);
        qr[0]=q0.x*QSC; qr[1]=q0.y*QSC; qr[2]=q0.z*QSC; qr[3]=q0.w*QSC;
        qr[4]=q1.x*QSC; qr[5]=q1.y*QSC; qr[6]=q1.z*QSC; qr[7]=q1.w*QSC;
        qr[8]=q2.x*QSC; qr[9]=q2.y*QSC; qr[10]=q2.z*QSC; qr[11]=q2.w*QSC;
        qr[12]=q3.x*QSC; qr[13]=q3.y*QSC; qr[14]=q3.z*QSC; qr[15]=q3.w*QSC;
    }
    float qe = 0.f;
    #pragma unroll
    for (int c = 0; c < CH; ++c) qe = fmaf(qr[c], We[h * CH + c], qe);   // uniform -> scalar
    const unsigned short* wr = wm + (i0 + r) * NN;

    float o[CH];
    #pragma unroll
    for (int c = 0; c < CH; ++c) o[c] = 0.f;
    float m = -1e30f, sum = 0.f, aw = 0.f;

    const float* kh = k + h * (NN * CH);
    const float* vh = v + h * (NN * CH);
    const int wb = w * 32;               // this wave's j-quarter within the chunk

    for (int ch = 0; ch < NN / CHK; ++ch) {
        const int jb = ch * CHK;
        {   // stage: threads 0..127 -> k rows, 128..255 -> v rows (one 64B row each)
            const int rr = t & 127;
            const float* src = ((t < 128) ? kh : vh) + (size_t)(jb + rr) * CH;
            float* dst = (t < 128) ? &kS[rr][0] : &vS[rr][0];
            const float4 sa = ((const float4*)src)[0];
            const float4 sb = ((const float4*)src)[1];
            const float4 sc = ((const float4*)src)[2];
            const float4 sd = ((const float4*)src)[3];
            *(float4*)(dst + 0)  = sa;
            *(float4*)(dst + 4)  = sb;
            *(float4*)(dst + 8)  = sc;
            *(float4*)(dst + 12) = sd;
        }
        __syncthreads();

        // QK^T for my 4 j's
        float d[4];
        #pragma unroll
        for (int q2 = 0; q2 < 4; ++q2) {
            const int jj = wb + js + 8 * q2;
            float acc = 0.f;
            #pragma unroll
            for (int c0 = 0; c0 < 4; ++c0) {
                const float4 kv = *(const float4*)&kS[jj][4 * c0];
                acc = fmaf(qr[4 * c0 + 0], kv.x, acc);
                acc = fmaf(qr[4 * c0 + 1], kv.y, acc);
                acc = fmaf(qr[4 * c0 + 2], kv.z, acc);
                acc = fmaf(qr[4 * c0 + 3], kv.w, acc);
            }
            d[q2] = acc;
        }
        // edge weight + mask -> s (exp2 domain)
        float s[4], wa[4];
        #pragma unroll
        for (int q2 = 0; q2 < 4; ++q2) {
            const float wv = bf16_to_f32(wr[jb + wb + js + 8 * q2]);   // sign = mask
            wa[q2] = fabsf(wv);
            s[q2] = (wv > 0.f) ? fmaf(qe, wa[q2], d[q2]) : -1e30f;
        }
        // online max + rescale + accumulate
        const float smax = fmaxf(fmaxf(s[0], s[1]), fmaxf(s[2], s[3]));
        const float mn = fmaxf(m, smax);
        const float f = __builtin_amdgcn_exp2f(m - mn);   // m=-1e30,mn real -> 0; both -1e30 -> 1 (o=0 anyway)
        sum *= f; aw *= f;
        #pragma unroll
        for (int c = 0; c < CH; ++c) o[c] *= f;
        m = mn;
        float p[4];
        #pragma unroll
        for (int q2 = 0; q2 < 4; ++q2) {
            p[q2] = (s[q2] > -1e29f) ? __builtin_amdgcn_exp2f(s[q2] - mn) : 0.f;   // explicit gate (avoid exp2(0) pollution)
            sum += p[q2];
            aw = fmaf(p[q2], wa[q2], aw);
        }
        // PV for my 4 j's
        #pragma unroll
        for (int q2 = 0; q2 < 4; ++q2) {
            const int jj = wb + js + 8 * q2;
            #pragma unroll
            for (int c0 = 0; c0 < 4; ++c0) {
                const float4 vv = *(const float4*)&vS[jj][4 * c0];
                o[4 * c0 + 0] = fmaf(p[q2], vv.x, o[4 * c0 + 0]);
                o[4 * c0 + 1] = fmaf(p[q2], vv.y, o[4 * c0 + 1]);
                o[4 * c0 + 2] = fmaf(p[q2], vv.z, o[4 * c0 + 2]);
                o[4 * c0 + 3] = fmaf(p[q2], vv.w, o[4 * c0 + 3]);
            }
        }
        __syncthreads();
    }

    // intra-wave merge over the 8 js-lanes (rescaled combine)
    #pragma unroll
    for (int off = 1; off < 8; off <<= 1) {
        const float mo = __shfl_xor(m, off);
        const float mn = fmaxf(m, mo);
        const float fs = __builtin_amdgcn_exp2f(m - mn);
        const float fo = __builtin_amdgcn_exp2f(mo - mn);
        sum = sum * fs + __shfl_xor(sum, off) * fo;
        aw  = aw  * fs + __shfl_xor(aw,  off) * fo;
        #pragma unroll
        for (int c = 0; c < CH; ++c)
            o[c] = o[c] * fs + __shfl_xor(o[c], off) * fo;
        m = mn;
    }
    if (js == 0) {       // dump wave-partial for (w, r)
        float* mp = &mrg[w][r][0];
        mp[0] = m; mp[1] = sum; mp[2] = aw;
        #pragma unroll
        for (int c = 0; c < CH; ++c) mp[3 + c] = o[c];
    }
    __syncthreads();

    // final combine: thread (r2, c) merges the 4 wave-partials and writes x
    if (t < TT * CH) {
        const int r2 = t >> 4, c = t & 15;
        const float m0 = mrg[0][r2][0], m1 = mrg[1][r2][0], m2 = mrg[2][r2][0], m3 = mrg[3][r2][0];
        const float ms = fmaxf(fmaxf(m0, m1), fmaxf(m2, m3));
        const float f0 = __builtin_amdgcn_exp2f(m0 - ms);
        const float f1 = __builtin_amdgcn_exp2f(m1 - ms);
        const float f2 = __builtin_amdgcn_exp2f(m2 - ms);
        const float f3 = __builtin_amdgcn_exp2f(m3 - ms);
        const float sums = f0 * mrg[0][r2][1] + f1 * mrg[1][r2][1] + f2 * mrg[2][r2][1] + f3 * mrg[3][r2][1];
        const float aws  = f0 * mrg[0][r2][2] + f1 * mrg[1][r2][2] + f2 * mrg[2][r2][2] + f3 * mrg[3][r2][2];
        const float oc   = f0 * mrg[0][r2][3 + c] + f1 * mrg[1][r2][3 + c]
                         + f2 * mrg[2][r2][3 + c] + f3 * mrg[3][r2][3 + c];
        const float inv = (ms > -1e29f) ? 1.f / sums : 0.f;   // all-masked row -> 0
        const int idx = (i0 + r2) * HD + h * CH + c;
        x[idx] = x[idx] + skip[idx] + oc * inv + (aws * inv) * We[h * CH + c];
    }
}

// ---------------- launch ----------------
extern "C" void kernel_launch(void* const* d_in, const int* in_sizes, int n_in,
                              void* d_out, int out_size, void* d_ws, size_t ws_size,
                              hipStream_t stream) {
    const float* ent = (const float*)d_in[2];
    const float* W1  = (const float*)d_in[3];
    const float* b1  = (const float*)d_in[4];
    const float* W2  = (const float*)d_in[5];
    const float* b2  = (const float*)d_in[6];
    const float* Wq  = (const float*)d_in[7];
    const float* bq  = (const float*)d_in[8];
    const float* Wk  = (const float*)d_in[9];
    const float* bk  = (const float*)d_in[10];
    const float* Wv  = (const float*)d_in[11];
    const float* bv  = (const float*)d_in[12];
    const float* We  = (const float*)d_in[13];
    const float* Ws  = (const float*)d_in[14];
    const float* bs  = (const float*)d_in[15];

    unsigned short* wm = (unsigned short*)d_ws;   // [1024][1024] bf16, sign = mask (2 MB)
    float* fb = (float*)d_ws + (NN * NN / 2);
    float* q  = fb;                               // [8][1024][16]  (reused as 'a' before layers)
    float* k  = q + NN * HD;                      //                (reused as 'b')
    float* v  = k + NN * HD;                      // [8][1024][16]
    float* sk = v + NN * HD;
    float* x  = (float*)d_out;                    // running entity state

    k_edge_ab<<<dim3(NN / ABM, 2), 256, 0, stream>>>(ent, W1, b1, q /*a*/, k /*b*/, x);
    k_edge_w<<<dim3(32, 64), 256, 0, stream>>>(q, k, W2, b2, wm);

    for (int l = 0; l < NLAYERS; ++l) {
        k_proj<<<dim3(NN / PBM, 4), 256, 0, stream>>>(x,
            Wq + l * HD * HD, bq + l * HD, Wk + l * HD * HD, bk + l * HD,
            Wv + l * HD * HD, bv + l * HD, Ws + l * HD * HD, bs + l * HD,
            q, k, v, sk);
        k_attn<<<dim3(NN / TT, NH), 256, 0, stream>>>(q, k, v, sk, wm, We + l * HD, x);
    }
}

// Round 12
// 107.205 us; speedup vs baseline: 1.4883x; 1.0473x over previous
//
#include <hip/hip_runtime.h>
#include <math.h>

#define NN 1024     // entities
#define HD 128      // hidden dim
#define NH 8        // heads
#define CH 16       // dim per head
#define NLAYERS 3

#define TT 8        // target rows per attention block
#define CHK 128     // j-chunk size staged in LDS
#define KSP 20      // kS/vS row stride (floats): 80B -> b128 reads conflict-free across js, 16B aligned
#define ALP 130     // k_edge_w al row stride
#define PBM 4       // k_proj rows per block
#define ABM 2       // k_edge_ab rows per block
#define QSC 0.36067376022224085f   // 0.25 * log2(e)

__device__ __forceinline__ float bf16_to_f32(unsigned short u) {
    union { unsigned int i; float f; } x; x.i = ((unsigned int)u) << 16; return x.f;
}
__device__ __forceinline__ unsigned short f32_to_bf16(float f) {
    union { float f; unsigned int i; } x; x.f = f;
    const unsigned int r = x.i + 0x7FFFu + ((x.i >> 16) & 1u);   // RNE
    return (unsigned short)(r >> 16);
}

// ---------------- K1: a = x@W1[:128], b = x@W1[128:] + b1; by==0 also copies x -> xout ----------------
__global__ __launch_bounds__(256) void k_edge_ab(
        const float* __restrict__ x, const float* __restrict__ W1,
        const float* __restrict__ b1, float* __restrict__ a, float* __restrict__ b,
        float* __restrict__ xout) {
    __shared__ float xt[HD][ABM];
    __shared__ float red[2][ABM][HD];
    const int r0 = blockIdx.x * ABM;
    const int cb = blockIdx.y;           // 0 -> a, 1 -> b
    const int t  = threadIdx.x;
    {
        const float xv = x[(r0 + (t >> 7)) * HD + (t & 127)];
        xt[t & 127][t >> 7] = xv;
        if (cb == 0) xout[(r0 + (t >> 7)) * HD + (t & 127)] = xv;   // fused x init
    }
    __syncthreads();
    const int c = t & 127, g = t >> 7;
    const float* wp = W1 + cb * HD * HD + g * 64 * HD + c;
    const float* xp = &xt[g * 64][0];
    float a0 = 0.f, a1 = 0.f;
    #pragma unroll 8
    for (int kk = 0; kk < 64; ++kk) {
        const float wv = wp[kk * HD];
        const float2 xv = *(const float2*)&xp[kk * ABM];
        a0 = fmaf(xv.x, wv, a0);
        a1 = fmaf(xv.y, wv, a1);
    }
    red[g][0][c] = a0; red[g][1][c] = a1;
    __syncthreads();
    if (t < HD) {
        float* dst = cb ? b : a;
        const float bias = cb ? b1[t] : 0.f;
        #pragma unroll
        for (int r = 0; r < ABM; ++r)
            dst[(r0 + r) * HD + t] = red[0][r][t] + red[1][r][t] + bias;
    }
}

// ---------------- K2: wm[t][s] = bf16( sign(mask) * sigmoid(logit[s][t]) ) ----------------
__global__ __launch_bounds__(256) void k_edge_w(
        const float* __restrict__ a, const float* __restrict__ bb,
        const float* __restrict__ W2, const float* __restrict__ b2,
        unsigned short* __restrict__ wm) {
    __shared__ float al[32][ALP];
    __shared__ float bl[16][HD];
    const int t = threadIdx.x;
    const int s0 = blockIdx.x * 32, t0 = blockIdx.y * 16;
    for (int ii = t; ii < 2048; ii += 256) {
        const int row = ii >> 6, col = (ii & 63) * 2;
        *(float2*)&al[row][col] = *(const float2*)&a[(s0 + row) * HD + col];
    }
    for (int ii = t; ii < 512; ii += 256) {
        const int row = ii >> 5, col = (ii & 31) * 4;
        *(float4*)&bl[row][col] = *(const float4*)&bb[(t0 + row) * HD + col];
    }
    __syncthreads();
    const int s = t & 31, tt = t >> 5;
    float acc0 = 0.f, acc1 = 0.f;
    #pragma unroll 2
    for (int h4 = 0; h4 < HD; h4 += 4) {
        const float4 w2 = *(const float4*)&W2[h4];
        const float2 avA = *(const float2*)&al[s][h4];
        const float2 avB = *(const float2*)&al[s][h4 + 2];
        const float4 b0v = *(const float4*)&bl[tt][h4];
        const float4 b1v = *(const float4*)&bl[tt + 8][h4];
        acc0 = fmaf(fmaxf(avA.x + b0v.x, 0.f), w2.x, acc0);
        acc0 = fmaf(fmaxf(avA.y + b0v.y, 0.f), w2.y, acc0);
        acc0 = fmaf(fmaxf(avB.x + b0v.z, 0.f), w2.z, acc0);
        acc0 = fmaf(fmaxf(avB.y + b0v.w, 0.f), w2.w, acc0);
        acc1 = fmaf(fmaxf(avA.x + b1v.x, 0.f), w2.x, acc1);
        acc1 = fmaf(fmaxf(avA.y + b1v.y, 0.f), w2.y, acc1);
        acc1 = fmaf(fmaxf(avB.x + b1v.z, 0.f), w2.z, acc1);
        acc1 = fmaf(fmaxf(avB.y + b1v.w, 0.f), w2.w, acc1);
    }
    const float bias = b2[0];
    const float l0 = acc0 + bias, l1 = acc1 + bias;
    const float w0 = 1.f / (1.f + __expf(-l0));
    const float w1 = 1.f / (1.f + __expf(-l1));
    wm[(t0 + tt    ) * NN + s0 + s] = f32_to_bf16((l0 > 0.f) ? w0 : -w0);   // sign encodes mask
    wm[(t0 + tt + 8) * NN + s0 + s] = f32_to_bf16((l1 > 0.f) ? w1 : -w1);
}

// ---------------- K3: projections q,k,v ([h][n][c]) + skip ----------------
__global__ __launch_bounds__(256) void k_proj(
        const float* __restrict__ x,
        const float* __restrict__ Wq, const float* __restrict__ bq,
        const float* __restrict__ Wk, const float* __restrict__ bk,
        const float* __restrict__ Wv, const float* __restrict__ bv,
        const float* __restrict__ Wsk, const float* __restrict__ bsk,
        float* __restrict__ q, float* __restrict__ k,
        float* __restrict__ v, float* __restrict__ skip) {
    __shared__ float xt[HD][PBM];
    __shared__ float red[2][PBM][HD];
    const int r0 = blockIdx.x * PBM;
    const int cb = blockIdx.y;           // 0..3 -> q,k,v,skip
    const int t  = threadIdx.x;
    {
        const int r = t >> 6, c2 = (t & 63) * 2;
        const float2 xv = *(const float2*)&x[(r0 + r) * HD + c2];
        xt[c2][r] = xv.x; xt[c2 + 1][r] = xv.y;
    }
    __syncthreads();
    const int c = t & 127, g = t >> 7;
    const float* W = (cb == 0) ? Wq : (cb == 1) ? Wk : (cb == 2) ? Wv : Wsk;
    const float* wp = W + g * 64 * HD + c;
    const float* xp = &xt[g * 64][0];
    float a0 = 0.f, a1 = 0.f, a2 = 0.f, a3 = 0.f;
    #pragma unroll 8
    for (int kk = 0; kk < 64; ++kk) {
        const float wv = wp[kk * HD];
        const float4 xv = *(const float4*)&xp[kk * PBM];
        a0 = fmaf(xv.x, wv, a0);
        a1 = fmaf(xv.y, wv, a1);
        a2 = fmaf(xv.z, wv, a2);
        a3 = fmaf(xv.w, wv, a3);
    }
    red[g][0][c] = a0; red[g][1][c] = a1; red[g][2][c] = a2; red[g][3][c] = a3;
    __syncthreads();
    if (t < HD) {
        const float* bptr = (cb == 0) ? bq : (cb == 1) ? bk : (cb == 2) ? bv : bsk;
        const float bias = bptr[t];
        #pragma unroll
        for (int r = 0; r < PBM; ++r) {
            const float val = red[0][r][t] + red[1][r][t] + bias;
            const int row = r0 + r;
            if (cb == 3) {
                skip[row * HD + t] = val;
            } else {
                const int hnc = (t >> 4) * (NN * CH) + row * CH + (t & 15);
                ((cb == 0) ? q : (cb == 1) ? k : v)[hnc] = val;
            }
        }
    }
}

// ---------------- K4: flash attention; double-buffered k/v chunks, 1 barrier/chunk ----------------
// grid (NN/TT, NH). Block: 4 waves; lane = (row r, j-slot js); online softmax + defer-max.
__global__ __launch_bounds__(256) void k_attn(
        const float* __restrict__ q, const float* __restrict__ k,
        const float* __restrict__ v, const float* __restrict__ skip,
        const unsigned short* __restrict__ wm, const float* __restrict__ We,
        float* __restrict__ x) {
    __shared__ float kS[2][CHK][KSP];    // 20 KB
    __shared__ float vS[2][CHK][KSP];    // 20 KB
    __shared__ float mrg[4][TT][20];     // 2.5 KB: per-wave partials {m,sum,aw,o[16]}
    const int i0 = blockIdx.x * TT;
    const int h  = blockIdx.y;
    const int t  = threadIdx.x;
    const int w  = t >> 6, l = t & 63;
    const int r  = l >> 3, js = l & 7;

    const float* kh = k + h * (NN * CH);
    const float* vh = v + h * (NN * CH);
    const int rr = t & 127;
    const float* sbase = (t < 128) ? kh : vh;

    // q row (broadcast within 8-lane group), scaled into exp2 domain
    float qr[CH];
    {
        const float* qp = q + h * (NN * CH) + (i0 + r) * CH;
        const float4 q0 = *(const float4*)(qp + 0);
        const float4 q1 = *(const float4*)(qp + 4);
        const float4 q2 = *(const float4*)(qp + 8);
        const float4 q3 = *(const float4*)(qp + 12);
        qr[0]=q0.x*QSC; qr[1]=q0.y*QSC; qr[2]=q0.z*QSC; qr[3]=q0.w*QSC;
        qr[4]=q1.x*QSC; qr[5]=q1.y*QSC; qr[6]=q1.z*QSC; qr[7]=q1.w*QSC;
        qr[8]=q2.x*QSC; qr[9]=q2.y*QSC; qr[10]=q2.z*QSC; qr[11]=q2.w*QSC;
        qr[12]=q3.x*QSC; qr[13]=q3.y*QSC; qr[14]=q3.z*QSC; qr[15]=q3.w*QSC;
    }
    float qe = 0.f;
    #pragma unroll
    for (int c = 0; c < CH; ++c) qe = fmaf(qr[c], We[h * CH + c], qe);   // uniform -> scalar
    const unsigned short* wr = wm + (i0 + r) * NN;

    float o[CH];
    #pragma unroll
    for (int c = 0; c < CH; ++c) o[c] = 0.f;
    float m = -1e30f, sum = 0.f, aw = 0.f;
    const int wb = w * 32;               // this wave's j-quarter within the chunk

    // prologue: stage chunk 0 into buf 0
    {
        const float* src = sbase + (size_t)rr * CH;
        float* dst = (t < 128) ? &kS[0][rr][0] : &vS[0][rr][0];
        ((float4*)dst)[0] = ((const float4*)src)[0];
        *(float4*)(dst + 4)  = ((const float4*)src)[1];
        *(float4*)(dst + 8)  = ((const float4*)src)[2];
        *(float4*)(dst + 12) = ((const float4*)src)[3];
    }
    __syncthreads();

    int buf = 0;
    for (int ch = 0; ch < NN / CHK; ++ch) {
        // stage next chunk into buf^1 (VMEM issued before compute; latency hidden)
        if (ch + 1 < NN / CHK) {
            const float* src = sbase + (size_t)((ch + 1) * CHK + rr) * CH;
            float* dst = (t < 128) ? &kS[buf ^ 1][rr][0] : &vS[buf ^ 1][rr][0];
            const float4 sa = ((const float4*)src)[0];
            const float4 sb = ((const float4*)src)[1];
            const float4 sc = ((const float4*)src)[2];
            const float4 sd = ((const float4*)src)[3];
            *(float4*)(dst + 0)  = sa;
            *(float4*)(dst + 4)  = sb;
            *(float4*)(dst + 8)  = sc;
            *(float4*)(dst + 12) = sd;
        }
        const int jb = ch * CHK;

        // QK^T for my 4 j's
        float d[4];
        #pragma unroll
        for (int q2 = 0; q2 < 4; ++q2) {
            const int jj = wb + js + 8 * q2;
            float acc = 0.f;
            #pragma unroll
            for (int c0 = 0; c0 < 4; ++c0) {
                const float4 kv = *(const float4*)&kS[buf][jj][4 * c0];
                acc = fmaf(qr[4 * c0 + 0], kv.x, acc);
                acc = fmaf(qr[4 * c0 + 1], kv.y, acc);
                acc = fmaf(qr[4 * c0 + 2], kv.z, acc);
                acc = fmaf(qr[4 * c0 + 3], kv.w, acc);
            }
            d[q2] = acc;
        }
        // edge weight + mask -> s (exp2 domain); masked -> -1e30 (underflows to p=0)
        float s[4], wa[4];
        #pragma unroll
        for (int q2 = 0; q2 < 4; ++q2) {
            const float wv = bf16_to_f32(wr[jb + wb + js + 8 * q2]);   // sign = mask
            wa[q2] = fabsf(wv);
            s[q2] = (wv > 0.f) ? fmaf(qe, wa[q2], d[q2]) : -1e30f;
        }
        // defer-max: rescale only when the running max grows
        const float smax = fmaxf(fmaxf(s[0], s[1]), fmaxf(s[2], s[3]));
        if (smax > m) {
            const float f = __builtin_amdgcn_exp2f(m - smax);   // first real chunk: exp2(-inf)=0 clears garbage
            sum *= f; aw *= f;
            #pragma unroll
            for (int c = 0; c < CH; ++c) o[c] *= f;
            m = smax;
        }
        float p[4];
        #pragma unroll
        for (int q2 = 0; q2 < 4; ++q2) {
            p[q2] = __builtin_amdgcn_exp2f(s[q2] - m);   // masked: underflow -> 0 (m real); m=-1e30 garbage killed later
            sum += p[q2];
            aw = fmaf(p[q2], wa[q2], aw);
        }
        // PV for my 4 j's
        #pragma unroll
        for (int q2 = 0; q2 < 4; ++q2) {
            const int jj = wb + js + 8 * q2;
            const float pq = p[q2];
            #pragma unroll
            for (int c0 = 0; c0 < 4; ++c0) {
                const float4 vv = *(const float4*)&vS[buf][jj][4 * c0];
                o[4 * c0 + 0] = fmaf(pq, vv.x, o[4 * c0 + 0]);
                o[4 * c0 + 1] = fmaf(pq, vv.y, o[4 * c0 + 1]);
                o[4 * c0 + 2] = fmaf(pq, vv.z, o[4 * c0 + 2]);
                o[4 * c0 + 3] = fmaf(pq, vv.w, o[4 * c0 + 3]);
            }
        }
        __syncthreads();     // stage(ch+1) drained (vmcnt0 at barrier) + all waves done reading buf
        buf ^= 1;
    }

    // intra-wave merge over the 8 js-lanes (rescaled combine)
    #pragma unroll
    for (int off = 1; off < 8; off <<= 1) {
        const float mo = __shfl_xor(m, off);
        const float mn = fmaxf(m, mo);
        const float fs = __builtin_amdgcn_exp2f(m - mn);
        const float fo = __builtin_amdgcn_exp2f(mo - mn);
        sum = sum * fs + __shfl_xor(sum, off) * fo;
        aw  = aw  * fs + __shfl_xor(aw,  off) * fo;
        #pragma unroll
        for (int c = 0; c < CH; ++c)
            o[c] = o[c] * fs + __shfl_xor(o[c], off) * fo;
        m = mn;
    }
    if (js == 0) {       // dump wave-partial for (w, r)
        float* mp = &mrg[w][r][0];
        mp[0] = m; mp[1] = sum; mp[2] = aw;
        #pragma unroll
        for (int c = 0; c < CH; ++c) mp[3 + c] = o[c];
    }
    __syncthreads();

    // final combine: thread (r2, c) merges the 4 wave-partials and writes x
    if (t < TT * CH) {
        const int r2 = t >> 4, c = t & 15;
        const float m0 = mrg[0][r2][0], m1 = mrg[1][r2][0], m2 = mrg[2][r2][0], m3 = mrg[3][r2][0];
        const float ms = fmaxf(fmaxf(m0, m1), fmaxf(m2, m3));
        const float f0 = __builtin_amdgcn_exp2f(m0 - ms);
        const float f1 = __builtin_amdgcn_exp2f(m1 - ms);
        const float f2 = __builtin_amdgcn_exp2f(m2 - ms);
        const float f3 = __builtin_amdgcn_exp2f(m3 - ms);
        const float sums = f0 * mrg[0][r2][1] + f1 * mrg[1][r2][1] + f2 * mrg[2][r2][1] + f3 * mrg[3][r2][1];
        const float aws  = f0 * mrg[0][r2][2] + f1 * mrg[1][r2][2] + f2 * mrg[2][r2][2] + f3 * mrg[3][r2][2];
        const float oc   = f0 * mrg[0][r2][3 + c] + f1 * mrg[1][r2][3 + c]
                         + f2 * mrg[2][r2][3 + c] + f3 * mrg[3][r2][3 + c];
        const float inv = (ms > -1e29f) ? 1.f / sums : 0.f;   // all-masked row -> 0
        const int idx = (i0 + r2) * HD + h * CH + c;
        x[idx] = x[idx] + skip[idx] + oc * inv + (aws * inv) * We[h * CH + c];
    }
}

// ---------------- launch ----------------
extern "C" void kernel_launch(void* const* d_in, const int* in_sizes, int n_in,
                              void* d_out, int out_size, void* d_ws, size_t ws_size,
                              hipStream_t stream) {
    const float* ent = (const float*)d_in[2];
    const float* W1  = (const float*)d_in[3];
    const float* b1  = (const float*)d_in[4];
    const float* W2  = (const float*)d_in[5];
    const float* b2  = (const float*)d_in[6];
    const float* Wq  = (const float*)d_in[7];
    const float* bq  = (const float*)d_in[8];
    const float* Wk  = (const float*)d_in[9];
    const float* bk  = (const float*)d_in[10];
    const float* Wv  = (const float*)d_in[11];
    const float* bv  = (const float*)d_in[12];
    const float* We  = (const float*)d_in[13];
    const float* Ws  = (const float*)d_in[14];
    const float* bs  = (const float*)d_in[15];

    unsigned short* wm = (unsigned short*)d_ws;   // [1024][1024] bf16, sign = mask (2 MB)
    float* fb = (float*)d_ws + (NN * NN / 2);
    float* q  = fb;                               // [8][1024][16]  (reused as 'a' before layers)
    float* k  = q + NN * HD;                      //                (reused as 'b')
    float* v  = k + NN * HD;                      // [8][1024][16]
    float* sk = v + NN * HD;
    float* x  = (float*)d_out;                    // running entity state

    k_edge_ab<<<dim3(NN / ABM, 2), 256, 0, stream>>>(ent, W1, b1, q /*a*/, k /*b*/, x);
    k_edge_w<<<dim3(32, 64), 256, 0, stream>>>(q, k, W2, b2, wm);

    for (int l = 0; l < NLAYERS; ++l) {
        k_proj<<<dim3(NN / PBM, 4), 256, 0, stream>>>(x,
            Wq + l * HD * HD, bq + l * HD, Wk + l * HD * HD, bk + l * HD,
            Wv + l * HD * HD, bv + l * HD, Ws + l * HD * HD, bs + l * HD,
            q, k, v, sk);
        k_attn<<<dim3(NN / TT, NH), 256, 0, stream>>>(q, k, v, sk, wm, We + l * HD, x);
    }
}